// Round 2
// baseline (376.406 us; speedup 1.0000x reference)
//
#include <hip/hip_runtime.h>
#include <stdint.h>

#define BATCH_N   131072
#define HID       256
#define SPIKE_DIM 128
#define COORD_DIM 64
#define IN_DIM    192
#define STEPS     25
#define TILE      32
#define BLOCK     256

typedef float f4  __attribute__((ext_vector_type(4)));
typedef short bf8 __attribute__((ext_vector_type(8)));
typedef unsigned short us4 __attribute__((ext_vector_type(4)));

// ws layout:
//   W0b  [256][192] bf16   at byte 0        (49152 ushorts = 96 KB)
//   W1T  [256][256] fp32   at float 24576   (65536 floats)
//   WoT  [256][64]  fp32   at float 90112   (16384 floats)
//   scalars           at float 106496: [0]=max(b1,0), [1]=max(W1+,0)
#define W1T_OFF  24576
#define WOT_OFF  90112
#define SCAL_OFF 106496

static __device__ __forceinline__ unsigned short f2bf(float f) {
  union { float f; unsigned u; } v; v.f = f;
  unsigned r = v.u + 0x7FFF + ((v.u >> 16) & 1);   // RNE
  return (unsigned short)(r >> 16);
}

__global__ __launch_bounds__(256)
void prep_kernel(const float* __restrict__ W0,
                 const float* __restrict__ W1,
                 const float* __restrict__ Wout,
                 const float* __restrict__ b1,
                 float* __restrict__ ws) {
  __shared__ float r1[256];
  __shared__ float r2[256];
  if (blockIdx.x == 512) {
    // screen scalars: w1pmax = max(max(W1),0) ; b1max0 = max(max(b1),0).
    // R1 post-mortem: the old per-thread strided 256-deep fmax chain was a
    // ~37 us serial latency wall (one block gates the kernel). Vectorized
    // coalesced f4 loads, independent accumulators, 64 pipelined iters.
    const int t = threadIdx.x;
    const f4* W14 = (const f4*)W1;         // 16384 f4
    f4 m4; m4.x = m4.y = m4.z = m4.w = 0.f; // >=0 fold built in
    #pragma unroll 4
    for (int i = t; i < HID*HID/4; i += 256) {
      f4 v = W14[i];
      m4.x = fmaxf(m4.x, v.x); m4.y = fmaxf(m4.y, v.y);
      m4.z = fmaxf(m4.z, v.z); m4.w = fmaxf(m4.w, v.w);
    }
    r1[t] = fmaxf(fmaxf(m4.x, m4.y), fmaxf(m4.z, m4.w));
    r2[t] = fmaxf(b1[t], 0.f);
    __syncthreads();
    for (int s = 128; s > 0; s >>= 1) {
      if (t < s) { r1[t] = fmaxf(r1[t], r1[t+s]); r2[t] = fmaxf(r2[t], r2[t+s]); }
      __syncthreads();
    }
    if (t == 0) { ws[SCAL_OFF] = r2[0]; ws[SCAL_OFF+1] = r1[0]; }
    return;
  }
  int idx = blockIdx.x * 256 + threadIdx.x;
  if (idx < HID*IN_DIM) {               // W0b elementwise (row-major, k-contig)
    ((unsigned short*)ws)[idx] = f2bf(W0[idx]);
  }
  int i1 = idx - HID*IN_DIM;            // W1T[j][i] = W1[i][j]
  if (i1 >= 0 && i1 < HID*HID) {
    int j = i1 >> 8, i = i1 & 255;
    ws[W1T_OFF + i1] = W1[i*HID + j];
  }
  int i2 = idx - (HID*IN_DIM + HID*HID);// WoT[k][c] = Wout[128+c][k]
  if (i2 >= 0 && i2 < HID*COORD_DIM) {
    int k = i2 >> 6, c = i2 & 63;
    ws[WOT_OFF + i2] = Wout[(SPIKE_DIM + c)*HID + k];
  }
}

__global__ __launch_bounds__(BLOCK, 8)
void snn_kernel(const float* __restrict__ spk,
                const float* __restrict__ crd,
                const float* __restrict__ W0,
                const float* __restrict__ b0,
                const float* __restrict__ b1,
                const float* __restrict__ bout,
                const float* __restrict__ ws,
                float* __restrict__ out) {
  // R2 structure: TILE=32, 4 waves, LDS ~12.9 KB -> 8 blocks/CU (thread-cap).
  // No c0 LDS round-trip: spike-superset counts come straight from the MFMA
  // accumulators (f32, un-rounded -> threshold 0.90 is a strict superset of
  // the old bf16 path's guarantee).
  __shared__ unsigned short xb[TILE*200];   // x staged bf16, stride 200
  __shared__ unsigned cnt2[16];             // [msub*4+quad][nhalf] packed counts

  const int tid  = threadIdx.x;
  const int lane = tid & 63;
  const int wv   = tid >> 6;            // wave 0..3
  const int quad = lane >> 4;
  const int l15  = lane & 15;
  const int e0   = blockIdx.x * TILE;
  const int i4   = lane * 4;

  // ---- stage x tile as bf16 into LDS ----
  {
    const f4* sp4 = (const f4*)(spk + (size_t)e0 * SPIKE_DIM);
    for (int t = tid; t < TILE*SPIKE_DIM/4; t += BLOCK) {
      int e = t >> 5, j = (t & 31) * 4;
      f4 v = __builtin_nontemporal_load(&sp4[t]);
      us4 h; h.x = f2bf(v.x); h.y = f2bf(v.y); h.z = f2bf(v.z); h.w = f2bf(v.w);
      *(us4*)&xb[e*200 + j] = h;
    }
    const f4* cr4 = (const f4*)(crd + (size_t)e0 * COORD_DIM);
    for (int t = tid; t < TILE*COORD_DIM/4; t += BLOCK) {
      int e = t >> 4, j = SPIKE_DIM + (t & 15) * 4;
      f4 v = __builtin_nontemporal_load(&cr4[t]);
      us4 h; h.x = f2bf(v.x); h.y = f2bf(v.y); h.z = f2bf(v.z); h.w = f2bf(v.w);
      *(us4*)&xb[e*200 + j] = h;
    }
  }
  __syncthreads();

  // ---- Phase A: c0 ~= x @ W0^T via bf16 MFMA (16x16x32) ----
  // wave tile: 16 elements (msub 0..1) x 128 neurons (nhalf, 8 subtiles of 16)
  const int msub  = wv >> 1;
  const int nhalf = wv & 1;
  const unsigned short* W0b = (const unsigned short*)ws;  // [256][192]

  // b0 for this lane's 8 neuron columns (independent of acc; issued early)
  float b0n[8];
  #pragma unroll
  for (int n = 0; n < 8; ++n) b0n[n] = b0[nhalf*128 + n*16 + l15];

  f4 acc[8];
  #pragma unroll
  for (int n = 0; n < 8; ++n) { acc[n].x = acc[n].y = acc[n].z = acc[n].w = 0.f; }

  #pragma unroll
  for (int kc = 0; kc < IN_DIM/32; ++kc) {
    bf8 a = *(const bf8*)&xb[(msub*16 + l15)*200 + kc*32 + quad*8];
    #pragma unroll
    for (int n = 0; n < 8; ++n) {
      bf8 b = *(const bf8*)&W0b[(size_t)(nhalf*128 + n*16 + l15)*IN_DIM + kc*32 + quad*8];
      acc[n] = __builtin_amdgcn_mfma_f32_16x16x32_bf16(a, b, acc[n], 0, 0, 0);
    }
  }

  // ---- spike-superset counts from accumulators ----
  // C/D layout: col(neuron)=l15, row(element)=msub*16+quad*4+reg.
  // Rigor: exact-spiking neuron has exact c0 >= 0.96; MFMA bf16-input error
  // <= ~0.05 (no output rounding now) -> acc+b0 >= 0.90 counts it.
  {
    unsigned p = 0;
    #pragma unroll
    for (int n = 0; n < 8; ++n) {
      p += (acc[n].x + b0n[n] >= 0.90f) ? 1u        : 0u;
      p += (acc[n].y + b0n[n] >= 0.90f) ? (1u<<8)  : 0u;
      p += (acc[n].z + b0n[n] >= 0.90f) ? (1u<<16) : 0u;
      p += (acc[n].w + b0n[n] >= 0.90f) ? (1u<<24) : 0u;
    }
    p += __shfl_xor(p, 1, 16);
    p += __shfl_xor(p, 2, 16);
    p += __shfl_xor(p, 4, 16);
    p += __shfl_xor(p, 8, 16);          // per-quad sum over 16 lanes (<=128/byte)
    if (l15 == 0) cnt2[(msub*4 + quad)*2 + nhalf] = p;
  }
  __syncthreads();

  // ---- Phase B: level-1 screen (no loads) -> stores; rare exact fallback ----
  // c1_i(t) <= max(b1,0) + nspk * max(W1+,0) < 0.97 => s1 == 0 => outputs
  // (0, b_out) EXACT. Garbage scalars fail closed into the exact path.
  const float b1mx = ws[SCAL_OFF];
  const float w1pm = ws[SCAL_OFF + 1];
  float bc = bout[SPIKE_DIM + lane];
  const int eb = wv * 8;

  unsigned fastm = 0;
  #pragma unroll
  for (int ee = 0; ee < 8; ++ee) {
    const int el = eb + ee;                    // 0..31
    const int base = ((el >> 4)*4 + ((el >> 2) & 3))*2;
    const int sh = (el & 3) * 8;
    unsigned nspk = ((cnt2[base] >> sh) & 255u) + ((cnt2[base+1] >> sh) & 255u);
    if (b1mx + w1pm * (float)nspk < 0.97f) fastm |= (1u << ee);
  }

  // bulk fast-path stores: no data deps, max outstanding writes
  #pragma unroll
  for (int ee = 0; ee < 8; ++ee) {
    if (fastm & (1u << ee)) {
      const int e = e0 + eb + ee;
      f4 z; z.x = z.y = z.z = z.w = 0.f;
      __builtin_nontemporal_store(z, (f4*)&out[(size_t)e*HID + i4]);
      __builtin_nontemporal_store(bc,
          &out[(size_t)BATCH_N*HID + (size_t)e*COORD_DIM + lane]);
    }
  }

  // rare (~P 3e-5/element): verbatim exact path
  if (__builtin_expect(fastm != 0xFFu, 0)) {
    const float* W1T = ws + W1T_OFF;
    const float* WoT = ws + WOT_OFF;
    f4 b0v = *(const f4*)&b0[i4];
    f4 b1v = *(const f4*)&b1[i4];
    for (int ee = 0; ee < 8; ++ee) {
      if (fastm & (1u << ee)) continue;
      const int e = e0 + eb + ee;

      // ---- exact c0 recompute from global x, W0 (serial FMA, j ascending)
      float cx = 0.f, cy = 0.f, cz = 0.f, cw = 0.f;
      const float* r0 = W0 + (size_t)(i4+0)*IN_DIM;
      const float* r1 = W0 + (size_t)(i4+1)*IN_DIM;
      const float* r2 = W0 + (size_t)(i4+2)*IN_DIM;
      const float* r3 = W0 + (size_t)(i4+3)*IN_DIM;
      const float* xs_ = spk + (size_t)e*SPIKE_DIM;
      const float* xc_ = crd + (size_t)e*COORD_DIM;
      for (int j = 0; j < SPIKE_DIM; ++j) {
        float xj = xs_[j];
        cx = fmaf(xj, r0[j], cx); cy = fmaf(xj, r1[j], cy);
        cz = fmaf(xj, r2[j], cz); cw = fmaf(xj, r3[j], cw);
      }
      for (int j = 0; j < COORD_DIM; ++j) {
        float xj = xc_[j];
        cx = fmaf(xj, r0[SPIKE_DIM+j], cx); cy = fmaf(xj, r1[SPIKE_DIM+j], cy);
        cz = fmaf(xj, r2[SPIKE_DIM+j], cz); cw = fmaf(xj, r3[SPIKE_DIM+j], cw);
      }
      const float c0x = cx + b0v.x, c0y = cy + b0v.y;
      const float c0z = cz + b0v.z, c0w = cw + b0v.w;

      // ---- honest 25-step simulation (exact)
      float v0x=0.f, v0y=0.f, v0z=0.f, v0w=0.f;
      float v1x=0.f, v1y=0.f, v1z=0.f, v1w=0.f;
      float s1x=0.f, s1y=0.f, s1z=0.f, s1w=0.f;
      unsigned long long mm;

      for (int t = 0; t < STEPS; ++t) {
        bool sp;
        unsigned long long m0, m1, m2, m3;
        v0x = __fmul_rn(0.7f, v0x) + __fmul_rn(0.3f, c0x);
        sp = (v0x >= 1.0f); m0 = __ballot(sp); if (sp) v0x = 0.f;
        v0y = __fmul_rn(0.7f, v0y) + __fmul_rn(0.3f, c0y);
        sp = (v0y >= 1.0f); m1 = __ballot(sp); if (sp) v0y = 0.f;
        v0z = __fmul_rn(0.7f, v0z) + __fmul_rn(0.3f, c0z);
        sp = (v0z >= 1.0f); m2 = __ballot(sp); if (sp) v0z = 0.f;
        v0w = __fmul_rn(0.7f, v0w) + __fmul_rn(0.3f, c0w);
        sp = (v0w >= 1.0f); m3 = __ballot(sp); if (sp) v0w = 0.f;

        float c1x = b1v.x, c1y = b1v.y, c1z = b1v.z, c1w = b1v.w;
        f4 wcur; wcur.x = wcur.y = wcur.z = wcur.w = 0.f;
        int have = 0;
        #define PROCQ(MASK, Q)                                                  \
          mm = (MASK);                                                          \
          while (mm) {                                                          \
            int l = __builtin_ctzll(mm); mm &= mm - 1;                          \
            f4 wn = *(const f4*)&W1T[(l*4 + (Q))*HID + i4];                     \
            if (have) { c1x += wcur.x; c1y += wcur.y; c1z += wcur.z; c1w += wcur.w; } \
            wcur = wn; have = 1;                                                \
          }
        PROCQ(m0, 0)
        PROCQ(m1, 1)
        PROCQ(m2, 2)
        PROCQ(m3, 3)
        #undef PROCQ
        if (have) { c1x += wcur.x; c1y += wcur.y; c1z += wcur.z; c1w += wcur.w; }

        v1x = __fmul_rn(0.7f, v1x) + __fmul_rn(0.3f, c1x);
        sp = (v1x >= 1.0f); s1x = sp ? 1.f : 0.f; if (sp) v1x = 0.f;
        v1y = __fmul_rn(0.7f, v1y) + __fmul_rn(0.3f, c1y);
        sp = (v1y >= 1.0f); s1y = sp ? 1.f : 0.f; if (sp) v1y = 0.f;
        v1z = __fmul_rn(0.7f, v1z) + __fmul_rn(0.3f, c1z);
        sp = (v1z >= 1.0f); s1z = sp ? 1.f : 0.f; if (sp) v1z = 0.f;
        v1w = __fmul_rn(0.7f, v1w) + __fmul_rn(0.3f, c1w);
        sp = (v1w >= 1.0f); s1w = sp ? 1.f : 0.f; if (sp) v1w = 0.f;
      }

      f4 res; res.x = s1x; res.y = s1y; res.z = s1z; res.w = s1w;
      __builtin_nontemporal_store(res, (f4*)&out[(size_t)e*HID + i4]);

      unsigned long long f0 = __ballot(s1x > 0.5f);
      unsigned long long f1 = __ballot(s1y > 0.5f);
      unsigned long long f2 = __ballot(s1z > 0.5f);
      unsigned long long f3 = __ballot(s1w > 0.5f);
      float cacc = bc;
      #define CPROCQ(MASK, Q)                                 \
        mm = (MASK);                                          \
        while (mm) {                                          \
          int l = __builtin_ctzll(mm); mm &= mm - 1;          \
          cacc += WoT[(l*4 + (Q))*COORD_DIM + lane];          \
        }
      CPROCQ(f0, 0)
      CPROCQ(f1, 1)
      CPROCQ(f2, 2)
      CPROCQ(f3, 3)
      #undef CPROCQ
      __builtin_nontemporal_store(cacc,
          &out[(size_t)BATCH_N*HID + (size_t)e*COORD_DIM + lane]);
    }
  }
}

extern "C" void kernel_launch(void* const* d_in, const int* in_sizes, int n_in,
                              void* d_out, int out_size, void* d_ws, size_t ws_size,
                              hipStream_t stream) {
  (void)in_sizes; (void)n_in; (void)out_size; (void)ws_size;
  const float* spk = (const float*)d_in[0];
  const float* crd = (const float*)d_in[1];
  const float* W0  = (const float*)d_in[2];
  const float* b0  = (const float*)d_in[3];
  const float* W1  = (const float*)d_in[4];
  const float* b1  = (const float*)d_in[5];
  const float* Wo  = (const float*)d_in[6];
  const float* bo  = (const float*)d_in[7];
  float* ws  = (float*)d_ws;
  float* out = (float*)d_out;

  hipLaunchKernelGGL(prep_kernel, dim3(513), dim3(256), 0, stream, W0, W1, Wo, b1, ws);
  hipLaunchKernelGGL(snn_kernel, dim3(BATCH_N/TILE), dim3(BLOCK), 0, stream,
                     spk, crd, W0, b0, b1, bo, ws, out);
}

// Round 3
// 304.289 us; speedup vs baseline: 1.2370x; 1.2370x over previous
//
#include <hip/hip_runtime.h>
#include <stdint.h>

#define BATCH_N   131072
#define HID       256
#define SPIKE_DIM 128
#define COORD_DIM 64
#define IN_DIM    192
#define STEPS     25
#define TILE      64
#define BLOCK     512

typedef float f4  __attribute__((ext_vector_type(4)));
typedef short bf8 __attribute__((ext_vector_type(8)));
typedef unsigned short us4 __attribute__((ext_vector_type(4)));

// ws layout:
//   W0b  [256][192] bf16   at byte 0        (49152 ushorts = 96 KB)
//   W1T  [256][256] fp32   at float 24576   (65536 floats)
//   WoT  [256][64]  fp32   at float 90112   (16384 floats)
//   scalars           at float 106496: [0]=max(b1,0), [1]=max(W1+,0)
#define W1T_OFF  24576
#define WOT_OFF  90112
#define SCAL_OFF 106496

static __device__ __forceinline__ unsigned short f2bf(float f) {
  union { float f; unsigned u; } v; v.f = f;
  unsigned r = v.u + 0x7FFF + ((v.u >> 16) & 1);   // RNE
  return (unsigned short)(r >> 16);
}

__global__ __launch_bounds__(256)
void prep_kernel(const float* __restrict__ W0,
                 const float* __restrict__ W1,
                 const float* __restrict__ Wout,
                 const float* __restrict__ b1,
                 float* __restrict__ ws) {
  __shared__ float r1[256];
  __shared__ float r2[256];
  if (blockIdx.x == 512) {
    // screen scalars: w1pmax = max(max(W1),0) ; b1max0 = max(max(b1),0).
    // Coalesced f4 loads, independent accumulators (R1 lesson: no serial
    // strided fmax chain — one slow block gates the kernel).
    const int t = threadIdx.x;
    const f4* W14 = (const f4*)W1;         // 16384 f4
    f4 m4; m4.x = m4.y = m4.z = m4.w = 0.f; // >=0 fold built in
    #pragma unroll 4
    for (int i = t; i < HID*HID/4; i += 256) {
      f4 v = W14[i];
      m4.x = fmaxf(m4.x, v.x); m4.y = fmaxf(m4.y, v.y);
      m4.z = fmaxf(m4.z, v.z); m4.w = fmaxf(m4.w, v.w);
    }
    r1[t] = fmaxf(fmaxf(m4.x, m4.y), fmaxf(m4.z, m4.w));
    r2[t] = fmaxf(b1[t], 0.f);
    __syncthreads();
    for (int s = 128; s > 0; s >>= 1) {
      if (t < s) { r1[t] = fmaxf(r1[t], r1[t+s]); r2[t] = fmaxf(r2[t], r2[t+s]); }
      __syncthreads();
    }
    if (t == 0) { ws[SCAL_OFF] = r2[0]; ws[SCAL_OFF+1] = r1[0]; }
    return;
  }
  int idx = blockIdx.x * 256 + threadIdx.x;
  if (idx < HID*IN_DIM) {               // W0b elementwise (row-major, k-contig)
    ((unsigned short*)ws)[idx] = f2bf(W0[idx]);
  }
  int i1 = idx - HID*IN_DIM;            // W1T[j][i] = W1[i][j]
  if (i1 >= 0 && i1 < HID*HID) {
    int j = i1 >> 8, i = i1 & 255;
    ws[W1T_OFF + i1] = W1[i*HID + j];
  }
  int i2 = idx - (HID*IN_DIM + HID*HID);// WoT[k][c] = Wout[128+c][k]
  if (i2 >= 0 && i2 < HID*COORD_DIM) {
    int k = i2 >> 6, c = i2 & 63;
    ws[WOT_OFF + i2] = Wout[(SPIKE_DIM + c)*HID + k];
  }
}

__global__ __launch_bounds__(BLOCK, 4)
void snn_kernel(const float* __restrict__ spk,
                const float* __restrict__ crd,
                const float* __restrict__ W0,
                const float* __restrict__ b0,
                const float* __restrict__ b1,
                const float* __restrict__ bout,
                const float* __restrict__ ws,
                float* __restrict__ out) {
  // R3 structure: wave -> 32 neurons x ALL 64 elements.
  //   * 12 B-fragments/wave (12 KB), preloaded into registers ONCE, each
  //     feeds 4 MFMAs (was: 48 loads, 1:1 with MFMA, VGPR=32 -> serial).
  //   * per-block B traffic = 96 KB minimum (waves read disjoint slices).
  //   * spike counts: packed 16-bit fields, quad shfl-reduce, LDS atomicAdd
  //     across the 8 waves (16-bit fields: adversarial 256-count can't wrap).
  __shared__ unsigned short xb[TILE*200];   // x staged bf16, stride 200
  __shared__ unsigned cnt2[32];             // [group 0..15][lo,hi] 16-bit fields

  const int tid  = threadIdx.x;
  const int lane = tid & 63;
  const int wv   = tid >> 6;            // wave 0..7
  const int quad = lane >> 4;
  const int l15  = lane & 15;
  const int e0   = blockIdx.x * TILE;
  const int i4   = lane * 4;

  if (tid < 32) cnt2[tid] = 0;

  // ---- stage x tile as bf16 into LDS ----
  {
    const f4* sp4 = (const f4*)(spk + (size_t)e0 * SPIKE_DIM);
    for (int t = tid; t < TILE*SPIKE_DIM/4; t += BLOCK) {
      int e = t >> 5, j = (t & 31) * 4;
      f4 v = __builtin_nontemporal_load(&sp4[t]);
      us4 h; h.x = f2bf(v.x); h.y = f2bf(v.y); h.z = f2bf(v.z); h.w = f2bf(v.w);
      *(us4*)&xb[e*200 + j] = h;
    }
    const f4* cr4 = (const f4*)(crd + (size_t)e0 * COORD_DIM);
    for (int t = tid; t < TILE*COORD_DIM/4; t += BLOCK) {
      int e = t >> 4, j = SPIKE_DIM + (t & 15) * 4;
      f4 v = __builtin_nontemporal_load(&cr4[t]);
      us4 h; h.x = f2bf(v.x); h.y = f2bf(v.y); h.z = f2bf(v.z); h.w = f2bf(v.w);
      *(us4*)&xb[e*200 + j] = h;
    }
  }
  __syncthreads();

  // ---- Phase A: c0 ~= x @ W0^T via bf16 MFMA (16x16x32) ----
  // wave wv owns neurons [wv*32, wv*32+32): nsub 0..1, all 4 element subtiles.
  const unsigned short* W0b = (const unsigned short*)ws;  // [256][192]

  float b0n[2];
  b0n[0] = b0[wv*32 + l15];
  b0n[1] = b0[wv*32 + 16 + l15];

  // preload all 12 B fragments (resident in regs; 12 loads in flight at once)
  bf8 bfr[2][6];
  #pragma unroll
  for (int n = 0; n < 2; ++n)
    #pragma unroll
    for (int kc = 0; kc < 6; ++kc)
      bfr[n][kc] = *(const bf8*)&W0b[(size_t)(wv*32 + n*16 + l15)*IN_DIM
                                     + kc*32 + quad*8];

  f4 acc[4][2];
  #pragma unroll
  for (int m = 0; m < 4; ++m)
    #pragma unroll
    for (int n = 0; n < 2; ++n) { acc[m][n].x = acc[m][n].y = acc[m][n].z = acc[m][n].w = 0.f; }

  #pragma unroll
  for (int kc = 0; kc < 6; ++kc) {
    #pragma unroll
    for (int m = 0; m < 4; ++m) {
      bf8 a = *(const bf8*)&xb[(m*16 + l15)*200 + kc*32 + quad*8];
      acc[m][0] = __builtin_amdgcn_mfma_f32_16x16x32_bf16(a, bfr[0][kc], acc[m][0], 0, 0, 0);
      acc[m][1] = __builtin_amdgcn_mfma_f32_16x16x32_bf16(a, bfr[1][kc], acc[m][1], 0, 0, 0);
    }
  }

  // ---- spike-superset counts from accumulators ----
  // C/D layout: col(neuron)=l15, row(element)=m*16+quad*4+reg.
  // Rigor: exact-spiking neuron has exact c0 >= 1.0001 (geometric sum);
  // bf16-input MFMA error <= ~0.05 (f32 accumulate, no output rounding)
  // -> acc+b0 >= 0.90 counts it (strict superset).
  #pragma unroll
  for (int m = 0; m < 4; ++m) {
    unsigned lo = 0, hi = 0;
    #pragma unroll
    for (int n = 0; n < 2; ++n) {
      lo += (acc[m][n].x + b0n[n] >= 0.90f) ? 1u        : 0u;
      lo += (acc[m][n].y + b0n[n] >= 0.90f) ? (1u<<16)  : 0u;
      hi += (acc[m][n].z + b0n[n] >= 0.90f) ? 1u        : 0u;
      hi += (acc[m][n].w + b0n[n] >= 0.90f) ? (1u<<16)  : 0u;
    }
    lo += __shfl_xor(lo, 1, 16); hi += __shfl_xor(hi, 1, 16);
    lo += __shfl_xor(lo, 2, 16); hi += __shfl_xor(hi, 2, 16);
    lo += __shfl_xor(lo, 4, 16); hi += __shfl_xor(hi, 4, 16);
    lo += __shfl_xor(lo, 8, 16); hi += __shfl_xor(hi, 8, 16);
    if (l15 == 0) {                      // one leader per quad
      atomicAdd(&cnt2[(m*4 + quad)*2 + 0], lo);
      atomicAdd(&cnt2[(m*4 + quad)*2 + 1], hi);
    }
  }
  __syncthreads();

  // ---- Phase B: level-1 screen (no loads) -> stores; rare exact fallback ----
  // c1_i(t) <= max(b1,0) + nspk * max(W1+,0) < 0.97 => s1 == 0 => outputs
  // (0, b_out) EXACT. Garbage scalars fail closed into the exact path.
  const float b1mx = ws[SCAL_OFF];
  const float w1pm = ws[SCAL_OFF + 1];
  float bc = bout[SPIKE_DIM + lane];
  const int eb = wv * 8;

  unsigned fastm = 0;
  #pragma unroll
  for (int ee = 0; ee < 8; ++ee) {
    const int el = eb + ee;                    // 0..63, wave-uniform
    unsigned w = cnt2[(el >> 2)*2 + ((el >> 1) & 1)];
    unsigned nspk = (w >> ((el & 1)*16)) & 0xFFFFu;
    if (b1mx + w1pm * (float)nspk < 0.97f) fastm |= (1u << ee);
  }

  // bulk fast-path stores: no data deps, max outstanding writes
  #pragma unroll
  for (int ee = 0; ee < 8; ++ee) {
    if (fastm & (1u << ee)) {
      const int e = e0 + eb + ee;
      f4 z; z.x = z.y = z.z = z.w = 0.f;
      __builtin_nontemporal_store(z, (f4*)&out[(size_t)e*HID + i4]);
      __builtin_nontemporal_store(bc,
          &out[(size_t)BATCH_N*HID + (size_t)e*COORD_DIM + lane]);
    }
  }

  // rare (~P 3e-5/element): verbatim exact path
  if (__builtin_expect(fastm != 0xFFu, 0)) {
    const float* W1T = ws + W1T_OFF;
    const float* WoT = ws + WOT_OFF;
    f4 b0v = *(const f4*)&b0[i4];
    f4 b1v = *(const f4*)&b1[i4];
    for (int ee = 0; ee < 8; ++ee) {
      if (fastm & (1u << ee)) continue;
      const int e = e0 + eb + ee;

      // ---- exact c0 recompute from global x, W0 (serial FMA, j ascending)
      float cx = 0.f, cy = 0.f, cz = 0.f, cw = 0.f;
      const float* r0 = W0 + (size_t)(i4+0)*IN_DIM;
      const float* r1 = W0 + (size_t)(i4+1)*IN_DIM;
      const float* r2 = W0 + (size_t)(i4+2)*IN_DIM;
      const float* r3 = W0 + (size_t)(i4+3)*IN_DIM;
      const float* xs_ = spk + (size_t)e*SPIKE_DIM;
      const float* xc_ = crd + (size_t)e*COORD_DIM;
      for (int j = 0; j < SPIKE_DIM; ++j) {
        float xj = xs_[j];
        cx = fmaf(xj, r0[j], cx); cy = fmaf(xj, r1[j], cy);
        cz = fmaf(xj, r2[j], cz); cw = fmaf(xj, r3[j], cw);
      }
      for (int j = 0; j < COORD_DIM; ++j) {
        float xj = xc_[j];
        cx = fmaf(xj, r0[SPIKE_DIM+j], cx); cy = fmaf(xj, r1[SPIKE_DIM+j], cy);
        cz = fmaf(xj, r2[SPIKE_DIM+j], cz); cw = fmaf(xj, r3[SPIKE_DIM+j], cw);
      }
      const float c0x = cx + b0v.x, c0y = cy + b0v.y;
      const float c0z = cz + b0v.z, c0w = cw + b0v.w;

      // ---- honest 25-step simulation (exact)
      float v0x=0.f, v0y=0.f, v0z=0.f, v0w=0.f;
      float v1x=0.f, v1y=0.f, v1z=0.f, v1w=0.f;
      float s1x=0.f, s1y=0.f, s1z=0.f, s1w=0.f;
      unsigned long long mm;

      for (int t = 0; t < STEPS; ++t) {
        bool sp;
        unsigned long long m0, m1, m2, m3;
        v0x = __fmul_rn(0.7f, v0x) + __fmul_rn(0.3f, c0x);
        sp = (v0x >= 1.0f); m0 = __ballot(sp); if (sp) v0x = 0.f;
        v0y = __fmul_rn(0.7f, v0y) + __fmul_rn(0.3f, c0y);
        sp = (v0y >= 1.0f); m1 = __ballot(sp); if (sp) v0y = 0.f;
        v0z = __fmul_rn(0.7f, v0z) + __fmul_rn(0.3f, c0z);
        sp = (v0z >= 1.0f); m2 = __ballot(sp); if (sp) v0z = 0.f;
        v0w = __fmul_rn(0.7f, v0w) + __fmul_rn(0.3f, c0w);
        sp = (v0w >= 1.0f); m3 = __ballot(sp); if (sp) v0w = 0.f;

        float c1x = b1v.x, c1y = b1v.y, c1z = b1v.z, c1w = b1v.w;
        f4 wcur; wcur.x = wcur.y = wcur.z = wcur.w = 0.f;
        int have = 0;
        #define PROCQ(MASK, Q)                                                  \
          mm = (MASK);                                                          \
          while (mm) {                                                          \
            int l = __builtin_ctzll(mm); mm &= mm - 1;                          \
            f4 wn = *(const f4*)&W1T[(l*4 + (Q))*HID + i4];                     \
            if (have) { c1x += wcur.x; c1y += wcur.y; c1z += wcur.z; c1w += wcur.w; } \
            wcur = wn; have = 1;                                                \
          }
        PROCQ(m0, 0)
        PROCQ(m1, 1)
        PROCQ(m2, 2)
        PROCQ(m3, 3)
        #undef PROCQ
        if (have) { c1x += wcur.x; c1y += wcur.y; c1z += wcur.z; c1w += wcur.w; }

        v1x = __fmul_rn(0.7f, v1x) + __fmul_rn(0.3f, c1x);
        sp = (v1x >= 1.0f); s1x = sp ? 1.f : 0.f; if (sp) v1x = 0.f;
        v1y = __fmul_rn(0.7f, v1y) + __fmul_rn(0.3f, c1y);
        sp = (v1y >= 1.0f); s1y = sp ? 1.f : 0.f; if (sp) v1y = 0.f;
        v1z = __fmul_rn(0.7f, v1z) + __fmul_rn(0.3f, c1z);
        sp = (v1z >= 1.0f); s1z = sp ? 1.f : 0.f; if (sp) v1z = 0.f;
        v1w = __fmul_rn(0.7f, v1w) + __fmul_rn(0.3f, c1w);
        sp = (v1w >= 1.0f); s1w = sp ? 1.f : 0.f; if (sp) v1w = 0.f;
      }

      f4 res; res.x = s1x; res.y = s1y; res.z = s1z; res.w = s1w;
      __builtin_nontemporal_store(res, (f4*)&out[(size_t)e*HID + i4]);

      unsigned long long f0 = __ballot(s1x > 0.5f);
      unsigned long long f1 = __ballot(s1y > 0.5f);
      unsigned long long f2 = __ballot(s1z > 0.5f);
      unsigned long long f3 = __ballot(s1w > 0.5f);
      float cacc = bc;
      #define CPROCQ(MASK, Q)                                 \
        mm = (MASK);                                          \
        while (mm) {                                          \
          int l = __builtin_ctzll(mm); mm &= mm - 1;          \
          cacc += WoT[(l*4 + (Q))*COORD_DIM + lane];          \
        }
      CPROCQ(f0, 0)
      CPROCQ(f1, 1)
      CPROCQ(f2, 2)
      CPROCQ(f3, 3)
      #undef CPROCQ
      __builtin_nontemporal_store(cacc,
          &out[(size_t)BATCH_N*HID + (size_t)e*COORD_DIM + lane]);
    }
  }
}

extern "C" void kernel_launch(void* const* d_in, const int* in_sizes, int n_in,
                              void* d_out, int out_size, void* d_ws, size_t ws_size,
                              hipStream_t stream) {
  (void)in_sizes; (void)n_in; (void)out_size; (void)ws_size;
  const float* spk = (const float*)d_in[0];
  const float* crd = (const float*)d_in[1];
  const float* W0  = (const float*)d_in[2];
  const float* b0  = (const float*)d_in[3];
  const float* W1  = (const float*)d_in[4];
  const float* b1  = (const float*)d_in[5];
  const float* Wo  = (const float*)d_in[6];
  const float* bo  = (const float*)d_in[7];
  float* ws  = (float*)d_ws;
  float* out = (float*)d_out;

  hipLaunchKernelGGL(prep_kernel, dim3(513), dim3(256), 0, stream, W0, W1, Wo, b1, ws);
  hipLaunchKernelGGL(snn_kernel, dim3(BATCH_N/TILE), dim3(BLOCK), 0, stream,
                     spk, crd, W0, b0, b1, bo, ws, out);
}